// Round 3
// baseline (136.475 us; speedup 1.0000x reference)
//
#include <hip/hip_runtime.h>

// NodeEncoder with interpolation, round 3.
//
// R2 lesson: LUT-in-LDS removed the VALU bound (154 -> 122 us) but we sit at
// 4.46 TB/s vs ~6.9 TB/s fill ceiling. Neither VALU (~7%) nor LDS (~25%) is
// binding; the output is a 512 MB write-once stream that churns L2/L3
// allocation. This round: nontemporal stores (nt bit) for the output,
// nontemporal loads for z (read-once), and unroll-4 for deeper MLP.
//
// Layout unchanged: 83-row x 16-col LUT in LDS (5.3 KB), 4 threads per atom,
// one float4 per thread -> each wave stores a contiguous aligned 1 KB span.

#define K_TAB 16
#define N_Z   83

typedef float v4f __attribute__((ext_vector_type(4)));

__global__ __launch_bounds__(256) void node_encode_kernel(
    const float* __restrict__ z_in,
    float* __restrict__ out,
    int n_atoms)
{
    __shared__ float lut[N_Z][K_TAB];   // 83 rows x 64 B

    // ---- init: threads 0..82 each build one row ----
    constexpr float tab[K_TAB] = {0.f, 1.f, 6.f, 7.f, 8.f, 11.f, 13.f, 14.f,
                                  16.f, 17.f, 26.f, 29.f, 47.f, 78.f, 79.f, 83.f};
    const int t = threadIdx.x;
    if (t < N_Z) {
        const float zf = (float)t;
        int j = 0;
        float zlo = tab[0];
        float zhi = tab[K_TAB - 1];
#pragma unroll
        for (int k = 0; k < K_TAB; ++k) {          // ascending: count < z, track z_lo
            const bool lt = (tab[k] < zf);
            j += lt ? 1 : 0;
            zlo = lt ? tab[k] : zlo;
        }
#pragma unroll
        for (int k = K_TAB - 2; k >= 0; --k) {     // descending: smallest entry >= z
            zhi = (tab[k] >= zf) ? tab[k] : zhi;
        }
        const bool exact = (zhi == zf);
        const float denom = exact ? 1.f : (zhi - zlo);
        const float inv   = 1.f / denom;
        const float whi   = exact ? 1.f : (zf - zlo) * inv;
        const float wlo   = exact ? 0.f : (zhi - zf) * inv;
        int jl = j - (exact ? 0 : 1);
        if (jl < 0) jl = 0;
#pragma unroll
        for (int c = 0; c < K_TAB; ++c) {
            lut[t][c] = (c == j ? whi : 0.f) + (c == jl ? wlo : 0.f);
        }
    }
    __syncthreads();

    // ---- hot loop: one float4 (4 columns) per thread per iteration ----
    const int total4 = n_atoms * 4;                   // float4 units in output
    const int stride = gridDim.x * blockDim.x;
    v4f* __restrict__ out4 = reinterpret_cast<v4f*>(out);

#pragma unroll 4
    for (int idx = blockIdx.x * blockDim.x + threadIdx.x; idx < total4; idx += stride) {
        const int atom = idx >> 2;
        const int cg   = idx & 3;
        const float zf = __builtin_nontemporal_load(&z_in[atom]);   // read-once stream
        const int   zi = (int)zf;
        const v4f v = *reinterpret_cast<const v4f*>(&lut[zi][cg << 2]);
        __builtin_nontemporal_store(v, &out4[idx]);                 // write-once stream
    }
}

extern "C" void kernel_launch(void* const* d_in, const int* in_sizes, int n_in,
                              void* d_out, int out_size, void* d_ws, size_t ws_size,
                              hipStream_t stream) {
    const float* z = (const float*)d_in[0];
    float* out = (float*)d_out;
    const int n_atoms = in_sizes[0];

    const int block = 256;
    const int grid = 2048;   // 8 blocks/CU x 256 CU = full residency, grid-stride the rest

    node_encode_kernel<<<grid, block, 0, stream>>>(z, out, n_atoms);
}

// Round 4
// 130.945 us; speedup vs baseline: 1.0422x; 1.0422x over previous
//
#include <hip/hip_runtime.h>

// NodeEncoder with interpolation, round 4.
//
// R3 lesson: nontemporal stores REGRESSED (122 -> 136 us) — the normal
// allocate+write-combine path beats nt on gfx950 for full-line streaming
// stores. Reverted.
//
// R4 change (single, clean): two INDEPENDENT iterations in flight per loop
// body (idx and idx+S). R2's body was one serial chain
// (load z -> cvt -> ds_read -> store); doubling the independent chains
// doubles outstanding memory ops per wave so waitcnt stalls on one chain
// hide under the other.
//
// Layout unchanged from R2: 83x16 f32 LUT in LDS (5.3 KB), 4 threads per
// atom, one float4 per thread -> each wave stores a contiguous 1 KB span.

#define K_TAB 16
#define N_Z   83

typedef float v4f __attribute__((ext_vector_type(4)));

__global__ __launch_bounds__(256) void node_encode_kernel(
    const float* __restrict__ z_in,
    float* __restrict__ out,
    int n_atoms)
{
    __shared__ float lut[N_Z][K_TAB];   // 83 rows x 64 B

    // ---- init: threads 0..82 each build one row ----
    constexpr float tab[K_TAB] = {0.f, 1.f, 6.f, 7.f, 8.f, 11.f, 13.f, 14.f,
                                  16.f, 17.f, 26.f, 29.f, 47.f, 78.f, 79.f, 83.f};
    const int t = threadIdx.x;
    if (t < N_Z) {
        const float zf = (float)t;
        int j = 0;
        float zlo = tab[0];
        float zhi = tab[K_TAB - 1];
#pragma unroll
        for (int k = 0; k < K_TAB; ++k) {          // ascending: count < z, track z_lo
            const bool lt = (tab[k] < zf);
            j += lt ? 1 : 0;
            zlo = lt ? tab[k] : zlo;
        }
#pragma unroll
        for (int k = K_TAB - 2; k >= 0; --k) {     // descending: smallest entry >= z
            zhi = (tab[k] >= zf) ? tab[k] : zhi;
        }
        const bool exact = (zhi == zf);
        const float denom = exact ? 1.f : (zhi - zlo);
        const float inv   = 1.f / denom;
        const float whi   = exact ? 1.f : (zf - zlo) * inv;
        const float wlo   = exact ? 0.f : (zhi - zf) * inv;
        int jl = j - (exact ? 0 : 1);
        if (jl < 0) jl = 0;
#pragma unroll
        for (int c = 0; c < K_TAB; ++c) {
            lut[t][c] = (c == j ? whi : 0.f) + (c == jl ? wlo : 0.f);
        }
    }
    __syncthreads();

    // ---- hot loop: two independent float4 iterations in flight ----
    const int total4 = n_atoms * 4;                   // float4 units in output
    const int S = gridDim.x * blockDim.x;
    v4f* __restrict__ out4 = reinterpret_cast<v4f*>(out);

    int idx = blockIdx.x * blockDim.x + threadIdx.x;
    for (; idx + S < total4; idx += 2 * S) {
        const int i0 = idx;
        const int i1 = idx + S;
        // independent chain 0
        const float z0 = z_in[i0 >> 2];
        // independent chain 1
        const float z1 = z_in[i1 >> 2];
        const int zi0 = (int)z0;
        const int zi1 = (int)z1;
        const v4f v0 = *reinterpret_cast<const v4f*>(&lut[zi0][(i0 & 3) << 2]);
        const v4f v1 = *reinterpret_cast<const v4f*>(&lut[zi1][(i1 & 3) << 2]);
        out4[i0] = v0;
        out4[i1] = v1;
    }
    if (idx < total4) {
        const float z0 = z_in[idx >> 2];
        const int zi0 = (int)z0;
        out4[idx] = *reinterpret_cast<const v4f*>(&lut[zi0][(idx & 3) << 2]);
    }
}

extern "C" void kernel_launch(void* const* d_in, const int* in_sizes, int n_in,
                              void* d_out, int out_size, void* d_ws, size_t ws_size,
                              hipStream_t stream) {
    const float* z = (const float*)d_in[0];
    float* out = (float*)d_out;
    const int n_atoms = in_sizes[0];

    const int block = 256;
    const int grid = 2048;   // 8 blocks/CU x 256 CU = full residency, grid-stride the rest

    node_encode_kernel<<<grid, block, 0, stream>>>(z, out, n_atoms);
}

// Round 5
// 109.615 us; speedup vs baseline: 1.2450x; 1.1946x over previous
//
#include <hip/hip_runtime.h>

// NodeEncoder with interpolation, round 5.
//
// R3 lesson: nt stores regress (write-combine path is better). R4 lesson:
// doubling independent load->store chains regresses (per-wave MLP is not the
// limiter; split store windows hurt page locality).
//
// R5 theory: the residual gap to the pure-write fill ceiling (4.46 vs
// 6.9 TB/s) is the fine-grained read/write interleave + the dependent
// global-load in every iteration. Fix: phase-separated streaming.
//   - Block owns contiguous chunks of 1024 atoms (grid-stride over chunks).
//   - Stage phase: one coalesced float4 z-load per thread -> LDS (T14 split:
//     next chunk's load issues BEFORE the store phase, hides under stores).
//   - Store phase: pure-store loop; z and LUT row both from LDS; each wave
//     stores contiguous 1 KB per instr; block writes a contiguous 256 KB run.
// No global loads inside the store loop; reads hit DRAM in 4 KB bursts.

#define K_TAB 16
#define N_Z   83
#define CHUNK 1024                 // atoms per phase (4 KB z, 256 KB out)
#define BLOCK 256
#define INNER (CHUNK * 4 / BLOCK)  // float4 stores per thread per phase = 16

typedef float v4f __attribute__((ext_vector_type(4)));

__global__ __launch_bounds__(BLOCK) void node_encode_kernel(
    const float* __restrict__ z_in,
    float* __restrict__ out,
    int n_atoms, int n_chunks)
{
    __shared__ float lut[N_Z][K_TAB];   // 5.3 KB
    __shared__ float zbuf[CHUNK];       // 4 KB

    const int tid = threadIdx.x;

    // ---- LUT init: threads 0..82 each build one row ----
    constexpr float tab[K_TAB] = {0.f, 1.f, 6.f, 7.f, 8.f, 11.f, 13.f, 14.f,
                                  16.f, 17.f, 26.f, 29.f, 47.f, 78.f, 79.f, 83.f};
    if (tid < N_Z) {
        const float zf = (float)tid;
        int j = 0;
        float zlo = tab[0];
        float zhi = tab[K_TAB - 1];
#pragma unroll
        for (int k = 0; k < K_TAB; ++k) {          // ascending: count < z, track z_lo
            const bool lt = (tab[k] < zf);
            j += lt ? 1 : 0;
            zlo = lt ? tab[k] : zlo;
        }
#pragma unroll
        for (int k = K_TAB - 2; k >= 0; --k) {     // descending: smallest entry >= z
            zhi = (tab[k] >= zf) ? tab[k] : zhi;
        }
        const bool exact = (zhi == zf);
        const float denom = exact ? 1.f : (zhi - zlo);
        const float inv   = 1.f / denom;
        const float whi   = exact ? 1.f : (zf - zlo) * inv;
        const float wlo   = exact ? 0.f : (zhi - zf) * inv;
        int jl = j - (exact ? 0 : 1);
        if (jl < 0) jl = 0;
#pragma unroll
        for (int c = 0; c < K_TAB; ++c) {
            lut[tid][c] = (c == j ? whi : 0.f) + (c == jl ? wlo : 0.f);
        }
    }

    v4f* __restrict__ out4 = reinterpret_cast<v4f*>(out);
    const int total4 = n_atoms * 4;

    // ---- prologue: load first chunk's z slice into registers ----
    int c = blockIdx.x;
    v4f zreg = {0.f, 0.f, 0.f, 0.f};
    if (c < n_chunks) {
        const int a0 = c * CHUNK + tid * 4;
        if (a0 + 3 < n_atoms) {
            zreg = *reinterpret_cast<const v4f*>(&z_in[a0]);
        } else {
#pragma unroll
            for (int e = 0; e < 4; ++e)
                if (a0 + e < n_atoms) zreg[e] = z_in[a0 + e];
        }
    }

    // ---- phase loop over this block's chunks ----
    for (; c < n_chunks; c += gridDim.x) {
        __syncthreads();                       // prev phase's zbuf readers done
        *reinterpret_cast<v4f*>(&zbuf[tid * 4]) = zreg;

        // issue NEXT chunk's z load now; latency hides under the store phase
        const int cn = c + gridDim.x;
        if (cn < n_chunks) {
            const int a0 = cn * CHUNK + tid * 4;
            if (a0 + 3 < n_atoms) {
                zreg = *reinterpret_cast<const v4f*>(&z_in[a0]);
            } else {
                v4f zt = {0.f, 0.f, 0.f, 0.f};
#pragma unroll
                for (int e = 0; e < 4; ++e)
                    if (a0 + e < n_atoms) zt[e] = z_in[a0 + e];
                zreg = zt;
            }
        }
        __syncthreads();                       // zbuf ready

        const int base4 = c * (CHUNK * 4);
        if (base4 + CHUNK * 4 <= total4) {
            // full chunk: tight pure-store loop, all addressing static
#pragma unroll
            for (int k = 0; k < INNER; ++k) {
                const int u  = k * BLOCK + tid;
                const int zi = (int)zbuf[u >> 2];
                const v4f v  = *reinterpret_cast<const v4f*>(&lut[zi][(u & 3) << 2]);
                out4[base4 + u] = v;
            }
        } else {
            // partial last chunk (only 1 of n_chunks): guarded
            for (int k = 0; k < INNER; ++k) {
                const int u = k * BLOCK + tid;
                const int g = base4 + u;
                if (g < total4) {
                    const int zi = (int)zbuf[u >> 2];
                    out4[g] = *reinterpret_cast<const v4f*>(&lut[zi][(u & 3) << 2]);
                }
            }
        }
    }
}

extern "C" void kernel_launch(void* const* d_in, const int* in_sizes, int n_in,
                              void* d_out, int out_size, void* d_ws, size_t ws_size,
                              hipStream_t stream) {
    const float* z = (const float*)d_in[0];
    float* out = (float*)d_out;
    const int n_atoms = in_sizes[0];

    const int n_chunks = (n_atoms + CHUNK - 1) / CHUNK;
    const int grid = 2048;   // full residency (8 blocks/CU), grid-stride chunks

    node_encode_kernel<<<grid, BLOCK, 0, stream>>>(z, out, n_atoms, n_chunks);
}